// Round 2
// baseline (196.438 us; speedup 1.0000x reference)
//
#include <hip/hip_runtime.h>
#include <hip/hip_bf16.h>

#define FIN 128
#define FOUT 64
#define TILE_ROWS 64       // rows per gemm block = 4 waves x 16

#define EPB 2048           // edges per chunk
#define NPB 64             // nodes per bucket (d >> 6)
#define NBUK_MAX 800
#define CAP 1408           // records cap per bucket (mean 1024, +12 sigma)

// Workspace layout (bytes):
//   [0, 6,400,000)        support : N*64 bf16
//   OFF_TOT   +3,200      tot     : NBUK int (bucket totals, atomic)
//   OFF_DONE  +64         done    : 1 int   (hist block counter)
//   OFF_BASES +3,200      bases   : (NBUK+1) int (exclusive prefix)
//   OFF_CUR   +3,200      cur     : NBUK int (global scatter cursors)
//   OFF_TMP   +6,400,000  tmp     : E int2 {src | dloc<<16, ev}
#define OFF_TOT   6400000
#define OFF_DONE  6403200
#define OFF_BASES 6403264
#define OFF_CUR   6406464
#define OFF_TMP   6409664

typedef short bf16x8 __attribute__((ext_vector_type(8)));
typedef float f32x4  __attribute__((ext_vector_type(4)));

__device__ inline ushort f32_to_bf16_rne(float f) {
    unsigned u = __float_as_uint(f);
    u += 0x7FFFu + ((u >> 16) & 1u);
    return (ushort)(u >> 16);
}
__device__ inline float bf16_to_f32(ushort h) {
    return __uint_as_float((unsigned)h << 16);
}

// ---------------------------------------------------------------------------
// Fused: blocks [0,GB) MFMA gemm (W staged to LDS bf16, transposed+swizzled);
// blocks [GB,..) dst histogram -> global bucket totals via atomicAdd.
// LAST hist block (done-counter) scans the NBUK totals -> bases[] & cur[].
// ---------------------------------------------------------------------------
union __align__(16) GemmHistSh {
    int    h[NBUK_MAX];        // 3.2 KB (hist branch; reused as scan buffer)
    ushort wt[FOUT * FIN];     // 16 KB  (gemm branch: WT[n][k], swizzled)
};

__global__ __launch_bounds__(256) void gemm_hist_kernel(
    const float* __restrict__ x, const float* __restrict__ t,
    const float* __restrict__ W, ushort* __restrict__ support, int N,
    const int* __restrict__ dst, int* __restrict__ tot, int* __restrict__ done,
    int* __restrict__ bases, int* __restrict__ cur,
    int E, int SBP, int NBUK, int GB)
{
    __shared__ GemmHistSh sh;
    const int tid = threadIdx.x;

    if (blockIdx.x >= GB) {
        // ---- histogram branch ----
        __shared__ int amLast;
        const int chunk = blockIdx.x - GB;
        for (int i = tid; i < NBUK; i += 256) sh.h[i] = 0;
        __syncthreads();
        const int e0 = chunk * EPB;
        for (int i = tid; i < EPB; i += 256) {
            int e = e0 + i;
            if (e < E) atomicAdd(&sh.h[dst[e] >> 6], 1);
        }
        __syncthreads();
        for (int i = tid; i < NBUK; i += 256)
            if (sh.h[i]) atomicAdd(&tot[i], sh.h[i]);

        // last-block detection: release own atomics, then bump done
        __threadfence();
        __syncthreads();
        if (tid == 0)
            amLast = (atomicAdd(done, 1) == SBP - 1);
        __syncthreads();
        if (!amLast) return;

        // ---- exclusive scan of NBUK totals (<=1024), one block ----
        __threadfence();
        int v[4]; int s = 0;
        #pragma unroll
        for (int k = 0; k < 4; ++k) {
            int j = tid * 4 + k;
            v[k] = (j < NBUK)
                 ? __hip_atomic_load(&tot[j], __ATOMIC_RELAXED,
                                     __HIP_MEMORY_SCOPE_AGENT)
                 : 0;
            s += v[k];
        }
        __syncthreads();            // done with sh.h as hist
        sh.h[tid] = s;
        __syncthreads();
        #pragma unroll
        for (int d = 1; d < 256; d <<= 1) {
            int add = (tid >= d) ? sh.h[tid - d] : 0;
            __syncthreads();
            sh.h[tid] += add;
            __syncthreads();
        }
        int ex = sh.h[tid] - s;     // exclusive prefix for this thread's 4
        #pragma unroll
        for (int k = 0; k < 4; ++k) {
            int j = tid * 4 + k;
            if (j < NBUK) { bases[j] = ex; cur[j] = ex; ex += v[k]; }
        }
        if (tid == 0) bases[NBUK] = E;
        return;
    }

    // ---- MFMA gemm branch ----
    const int lane = tid & 63;
    const int w    = tid >> 6;          // wave 0..3
    const int ln   = lane & 15;
    const int q    = lane >> 4;         // quad 0..3
    const int rowb = blockIdx.x * TILE_ROWS + w * 16;
    const int arow = rowb + ln;

    // Stage W -> LDS bf16, transposed WT[n][k]; 16B slot XOR-swizzled by n&7.
    for (int idx = tid; idx < FIN * FOUT; idx += 256) {
        int k = idx >> 6;          // 0..127   (idx = k*FOUT + n)
        int n = idx & 63;          // 0..63
        sh.wt[n * FIN + (k ^ ((n & 7) << 3))] = f32_to_bf16_rne(W[idx]);
    }
    __syncthreads();

    f32x4 acc[4];
    #pragma unroll
    for (int nt = 0; nt < 4; ++nt)
        #pragma unroll
        for (int r = 0; r < 4; ++r) acc[nt][r] = 0.f;

    const bool aok = (arow < N);
    const float* xrow = &x[(size_t)arow * FIN];

    #pragma unroll
    for (int kc = 0; kc < 4; ++kc) {
        float xs[8];
        #pragma unroll
        for (int j = 0; j < 8; ++j) xs[j] = 0.f;
        if (aok) {
            float4 x0 = *(const float4*)&xrow[kc * 32 + q * 8];
            float4 x1 = *(const float4*)&xrow[kc * 32 + q * 8 + 4];
            xs[0] = x0.x; xs[1] = x0.y; xs[2] = x0.z; xs[3] = x0.w;
            xs[4] = x1.x; xs[5] = x1.y; xs[6] = x1.z; xs[7] = x1.w;
        }
        bf16x8 a;
        #pragma unroll
        for (int j = 0; j < 8; ++j) a[j] = (short)f32_to_bf16_rne(xs[j]);

        const int k0 = kc * 32 + q * 8;
        #pragma unroll
        for (int nt = 0; nt < 4; ++nt) {
            bf16x8 b = *(const bf16x8*)
                &sh.wt[(nt * 16 + ln) * FIN + (k0 ^ ((ln & 7) << 3))];
            acc[nt] = __builtin_amdgcn_mfma_f32_16x16x32_bf16(a, b, acc[nt], 0, 0, 0);
        }
    }

    // epilogue: D[m=q*4+reg][n=ln]; scale by t[row]; store bf16
    #pragma unroll
    for (int reg = 0; reg < 4; ++reg) {
        int r = rowb + q * 4 + reg;
        if (r < N) {
            float tv = t[r];
            #pragma unroll
            for (int nt = 0; nt < 4; ++nt)
                support[(size_t)r * FOUT + nt * 16 + ln] =
                    f32_to_bf16_rne(acc[nt][reg] * tv);
        }
    }
}

// ---------------------------------------------------------------------------
// scatter: per chunk, LDS-stage records + local hist, reserve per-bucket
// ranges via ONE returning atomicAdd per present bucket, place via LDS
// cursors. tmp stays globally bucket-contiguous.
// rec = {src | (d&63)<<16, ev_bits}   (src < 65536: N = 50000 ok)
// ---------------------------------------------------------------------------
__global__ __launch_bounds__(256) void scatter_kernel(
    const int* __restrict__ src, const int* __restrict__ dst,
    const float* __restrict__ ev, int* __restrict__ cur,
    int2* __restrict__ tmp, int E, int NBUK)
{
    __shared__ int2   stage[EPB];        // 16 KB
    __shared__ ushort bkt[EPB];          // 4 KB
    __shared__ int    h[NBUK_MAX];       // 3.2 KB
    __shared__ int    c[NBUK_MAX];       // 3.2 KB

    const int tid = threadIdx.x;
    const int e0  = blockIdx.x * EPB;

    for (int i = tid; i < NBUK; i += 256) h[i] = 0;
    __syncthreads();

    // pass 1: stage + local count
    for (int i = tid; i < EPB; i += 256) {
        int e = e0 + i;
        if (e < E) {
            int d = dst[e];
            int j = d >> 6;
            stage[i] = make_int2(src[e] | ((d & (NPB - 1)) << 16),
                                 __float_as_int(ev[e]));
            bkt[i] = (ushort)j;
            atomicAdd(&h[j], 1);
        } else {
            bkt[i] = 0xFFFF;
        }
    }
    __syncthreads();

    // pass 2: reserve contiguous ranges in each bucket's global region
    for (int j = tid; j < NBUK; j += 256) {
        int hj = h[j];
        if (hj) c[j] = atomicAdd(&cur[j], hj);
    }
    __syncthreads();

    // pass 3: place
    for (int i = tid; i < EPB; i += 256) {
        if (bkt[i] != 0xFFFF) {
            int pos = atomicAdd(&c[bkt[i]], 1);
            tmp[pos] = stage[i];
        }
    }
}

// ---------------------------------------------------------------------------
// bucket_gather: one block per 64-node bucket. tmp read once into LDS;
// count -> wave-0 shfl scan (64 wide) -> reorder -> register-walk with
// 8-deep MLP and wave-uniform node-boundary flush. No float atomics.
// ---------------------------------------------------------------------------
__global__ __launch_bounds__(256) void bucket_gather_kernel(
    const int* __restrict__ bases, const int2* __restrict__ tmp,
    const ushort* __restrict__ support, const float* __restrict__ bias,
    float* __restrict__ out, int E, int N, int NBUK)
{
    __shared__ int2 raw[CAP];           // 11 KB
    __shared__ int2 sorted[CAP];        // 11 KB
    __shared__ int  cnt[NPB];
    __shared__ int  starts[NPB + 1];
    __shared__ int  cur[NPB];

    const int tid   = threadIdx.x;
    const int w     = tid >> 6;
    const int lane  = tid & 63;
    const int B     = blockIdx.x;
    const int node0 = B * NPB;

    const int base   = bases[B];
    const int endB   = bases[B + 1];
    const int nrec   = endB - base;
    const int placed = (nrec < CAP) ? nrec : CAP;

    if (tid < NPB) cnt[tid] = 0;
    __syncthreads();

    // single global read of tmp: stage + count
    for (int i = tid; i < placed; i += 256) {
        int2 r = tmp[base + i];
        raw[i] = r;
        atomicAdd(&cnt[(r.x >> 16) & (NPB - 1)], 1);
    }
    __syncthreads();

    // wave-0 shfl scan over 64 counters
    if (tid < 64) {
        int v   = cnt[tid];
        int val = v;
        #pragma unroll
        for (int d = 1; d < NPB; d <<= 1) {
            int n = __shfl_up(val, d);
            if (tid >= d) val += n;
        }
        starts[tid] = val - v;
        cur[tid]    = val - v;
        if (tid == 0) starts[NPB] = placed;
    }
    __syncthreads();

    // reorder LDS -> LDS
    for (int i = tid; i < placed; i += 256) {
        int2 r  = raw[i];
        int pos = atomicAdd(&cur[(r.x >> 16) & (NPB - 1)], 1);
        sorted[pos] = r;
    }
    __syncthreads();

    // walk: wave w owns nodes [w*16, (w+1)*16) == records [rbeg, rend)
    const float bv = bias[lane];
    const int rbeg = starts[w * 16];
    const int rend = starts[w * 16 + 16];

    float accv = 0.f;
    int   curn = -1;

    int i = rbeg;
    // 8-deep MLP: issue 8 independent support-row gathers, then walk.
    while (i + 8 <= rend) {
        int2 r[8];
        #pragma unroll
        for (int u = 0; u < 8; ++u) r[u] = sorted[i + u];
        float v[8];
        #pragma unroll
        for (int u = 0; u < 8; ++u)
            v[u] = bf16_to_f32(support[(size_t)(r[u].x & 0xFFFF) * FOUT + lane]);
        #pragma unroll
        for (int u = 0; u < 8; ++u) {
            int n = (r[u].x >> 16) & (NPB - 1);     // wave-uniform
            if (n != curn) {
                if (curn >= 0 && node0 + curn < N)
                    out[(size_t)(node0 + curn) * FOUT + lane] = accv + bv;
                curn = n;
                accv = 0.f;
            }
            accv += v[u] * __int_as_float(r[u].y);
        }
        i += 8;
    }
    while (i < rend) {
        int2 a = sorted[i];
        float va = bf16_to_f32(support[(size_t)(a.x & 0xFFFF) * FOUT + lane]);
        int n = (a.x >> 16) & (NPB - 1);
        if (n != curn) {
            if (curn >= 0 && node0 + curn < N)
                out[(size_t)(node0 + curn) * FOUT + lane] = accv + bv;
            curn = n;
            accv = 0.f;
        }
        accv += va * __int_as_float(a.y);
        ++i;
    }
    if (curn >= 0 && node0 + curn < N)
        out[(size_t)(node0 + curn) * FOUT + lane] = accv + bv;

    // zero-count nodes get bias rows
    for (int n = w; n < NPB; n += 4) {
        int node = node0 + n;
        if (node < N && cnt[n] == 0)
            out[(size_t)node * FOUT + lane] = bv;
    }

    // overflow fallback (never triggers at this size; kept for correctness)
    if (nrec > CAP) {
        __threadfence();
        __syncthreads();
        for (int j = base + CAP + tid; j < endB; j += 256) {
            int2 r = tmp[j];
            int node = node0 + ((r.x >> 16) & (NPB - 1));
            float wgt = __int_as_float(r.y);
            for (int f = 0; f < FOUT; ++f) {
                float v = bf16_to_f32(support[(size_t)(r.x & 0xFFFF) * FOUT + f]);
                atomicAdd(&out[(size_t)node * FOUT + f], v * wgt);
            }
        }
    }
}

extern "C" void kernel_launch(void* const* d_in, const int* in_sizes, int n_in,
                              void* d_out, int out_size, void* d_ws, size_t ws_size,
                              hipStream_t stream) {
    const float* x    = (const float*)d_in[0];
    const float* t    = (const float*)d_in[1];
    const int*   src  = (const int*)d_in[2];
    const int*   dst  = (const int*)d_in[3];
    const float* ev   = (const float*)d_in[4];
    const float* W    = (const float*)d_in[5];
    const float* bias = (const float*)d_in[6];
    float* out = (float*)d_out;

    const int N = in_sizes[1];   // 50000
    const int E = in_sizes[2];   // 800000

    char*   ws      = (char*)d_ws;
    ushort* support = (ushort*)ws;
    int*    tot     = (int*)(ws + OFF_TOT);
    int*    done    = (int*)(ws + OFF_DONE);
    int*    bases   = (int*)(ws + OFF_BASES);
    int*    cur     = (int*)(ws + OFF_CUR);
    int2*   tmp     = (int2*)(ws + OFF_TMP);

    const int GB   = (N + TILE_ROWS - 1) / TILE_ROWS;       // 782
    const int SBP  = (E + EPB - 1) / EPB;                   // 391
    const int NBUK = (N + NPB - 1) / NPB;                   // 782

    // zero bucket totals + done counter (3.3 KB, graph-capturable)
    hipMemsetAsync(ws + OFF_TOT, 0, OFF_BASES - OFF_TOT, stream);

    // 1) fused: MFMA gemm + bucket totals; last hist block scans -> bases/cur
    gemm_hist_kernel<<<GB + SBP, 256, 0, stream>>>(
        x, t, W, support, N, dst, tot, done, bases, cur, E, SBP, NBUK, GB);

    // 2) scatter into bucket-ordered tmp (global cursor reservation)
    scatter_kernel<<<SBP, 256, 0, stream>>>(src, dst, ev, cur, tmp, E, NBUK);

    // 3) per-bucket LDS sort + register-walk accumulate -> out (+bias)
    bucket_gather_kernel<<<NBUK, 256, 0, stream>>>(
        bases, tmp, support, bias, out, E, N, NBUK);
}

// Round 3
// 151.322 us; speedup vs baseline: 1.2981x; 1.2981x over previous
//
#include <hip/hip_runtime.h>
#include <hip/hip_bf16.h>

#define FIN 128
#define FOUT 64
#define TILE_ROWS 64       // rows per gemm block = 4 waves x 16

#define EPB 2048           // edges per chunk
#define NPB 64             // nodes per bucket (d >> 6)
#define NBUK_MAX 800
#define CAP 1408           // records cap per bucket (mean 1024, +12 sigma)

// Workspace layout (bytes):
//   [0, 6,400,000)        support : N*64 bf16
//   OFF_TOT   +3,200      tot     : NBUK int (bucket totals, atomic)
//   OFF_DONE  +64         done    : 1 int   (hist block counter)
//   OFF_BASES +3,200      bases   : (NBUK+1) int (exclusive prefix)
//   OFF_CUR   +3,200      cur     : NBUK int (global scatter cursors)
//   OFF_TMP   +6,400,000  tmp     : E int2 {src | dloc<<16, ev}
#define OFF_TOT   6400000
#define OFF_DONE  6403200
#define OFF_BASES 6403264
#define OFF_CUR   6406464
#define OFF_TMP   6409664

typedef short bf16x8 __attribute__((ext_vector_type(8)));
typedef float f32x4  __attribute__((ext_vector_type(4)));

__device__ inline ushort f32_to_bf16_rne(float f) {
    unsigned u = __float_as_uint(f);
    u += 0x7FFFu + ((u >> 16) & 1u);
    return (ushort)(u >> 16);
}
__device__ inline float bf16_to_f32(ushort h) {
    return __uint_as_float((unsigned)h << 16);
}

// ---------------------------------------------------------------------------
// Fused: blocks [0,SBP) dst histogram -> global bucket totals via atomicAdd
// (hist FIRST so the last-block scan overlaps GEMM work);
// blocks [SBP,..) MFMA gemm (W staged to LDS bf16, transposed+swizzled).
// NO __threadfence: tot/done traffic is all device-scope atomics, which
// execute at the cross-XCD coherence point; on gfx95x an agent fence would
// emit buffer_wbl2/buffer_inv (full L2 writeback/invalidate) 391 times --
// that was R2's 75 us stall. s_waitcnt vmcnt(0) per thread is sufficient
// ordering for atomic->atomic release.
// ---------------------------------------------------------------------------
union __align__(16) GemmHistSh {
    int    h[NBUK_MAX];        // 3.2 KB (hist branch; reused as scan buffer)
    ushort wt[FOUT * FIN];     // 16 KB  (gemm branch: WT[n][k], swizzled)
};

__global__ __launch_bounds__(256) void gemm_hist_kernel(
    const float* __restrict__ x, const float* __restrict__ t,
    const float* __restrict__ W, ushort* __restrict__ support, int N,
    const int* __restrict__ dst, int* __restrict__ tot, int* __restrict__ done,
    int* __restrict__ bases, int* __restrict__ cur,
    int E, int SBP, int NBUK, int GB)
{
    __shared__ GemmHistSh sh;
    const int tid = threadIdx.x;

    if (blockIdx.x < (unsigned)SBP) {
        // ---- histogram branch ----
        __shared__ int amLast;
        const int chunk = blockIdx.x;
        for (int i = tid; i < NBUK; i += 256) sh.h[i] = 0;
        __syncthreads();
        const int e0 = chunk * EPB;
        for (int i = tid; i < EPB; i += 256) {
            int e = e0 + i;
            if (e < E) atomicAdd(&sh.h[dst[e] >> 6], 1);
        }
        __syncthreads();
        for (int i = tid; i < NBUK; i += 256)
            if (sh.h[i]) atomicAdd(&tot[i], sh.h[i]);

        // release own tot atomics: drain VMEM queue only (atomics complete
        // at the coherence point; no cache maintenance needed)
        asm volatile("s_waitcnt vmcnt(0)" ::: "memory");
        __syncthreads();
        if (tid == 0)
            amLast = (atomicAdd(done, 1) == SBP - 1);
        __syncthreads();
        if (!amLast) return;

        // ---- exclusive scan of NBUK totals (<=1024), one block ----
        int v[4]; int s = 0;
        #pragma unroll
        for (int k = 0; k < 4; ++k) {
            int j = tid * 4 + k;
            v[k] = (j < NBUK)
                 ? __hip_atomic_load(&tot[j], __ATOMIC_RELAXED,
                                     __HIP_MEMORY_SCOPE_AGENT)
                 : 0;
            s += v[k];
        }
        __syncthreads();            // done with sh.h as hist
        sh.h[tid] = s;
        __syncthreads();
        #pragma unroll
        for (int d = 1; d < 256; d <<= 1) {
            int add = (tid >= d) ? sh.h[tid - d] : 0;
            __syncthreads();
            sh.h[tid] += add;
            __syncthreads();
        }
        int ex = sh.h[tid] - s;     // exclusive prefix for this thread's 4
        #pragma unroll
        for (int k = 0; k < 4; ++k) {
            int j = tid * 4 + k;
            if (j < NBUK) { bases[j] = ex; cur[j] = ex; ex += v[k]; }
        }
        if (tid == 0) bases[NBUK] = E;
        return;
    }

    // ---- MFMA gemm branch ----
    const int gb   = blockIdx.x - SBP;
    const int lane = tid & 63;
    const int w    = tid >> 6;          // wave 0..3
    const int ln   = lane & 15;
    const int q    = lane >> 4;         // quad 0..3
    const int rowb = gb * TILE_ROWS + w * 16;
    const int arow = rowb + ln;

    // Stage W -> LDS bf16, transposed WT[n][k]; 16B slot XOR-swizzled by n&7.
    for (int idx = tid; idx < FIN * FOUT; idx += 256) {
        int k = idx >> 6;          // 0..127   (idx = k*FOUT + n)
        int n = idx & 63;          // 0..63
        sh.wt[n * FIN + (k ^ ((n & 7) << 3))] = f32_to_bf16_rne(W[idx]);
    }
    __syncthreads();

    f32x4 acc[4];
    #pragma unroll
    for (int nt = 0; nt < 4; ++nt)
        #pragma unroll
        for (int r = 0; r < 4; ++r) acc[nt][r] = 0.f;

    const bool aok = (arow < N);
    const float* xrow = &x[(size_t)arow * FIN];

    #pragma unroll
    for (int kc = 0; kc < 4; ++kc) {
        float xs[8];
        #pragma unroll
        for (int j = 0; j < 8; ++j) xs[j] = 0.f;
        if (aok) {
            float4 x0 = *(const float4*)&xrow[kc * 32 + q * 8];
            float4 x1 = *(const float4*)&xrow[kc * 32 + q * 8 + 4];
            xs[0] = x0.x; xs[1] = x0.y; xs[2] = x0.z; xs[3] = x0.w;
            xs[4] = x1.x; xs[5] = x1.y; xs[6] = x1.z; xs[7] = x1.w;
        }
        bf16x8 a;
        #pragma unroll
        for (int j = 0; j < 8; ++j) a[j] = (short)f32_to_bf16_rne(xs[j]);

        const int k0 = kc * 32 + q * 8;
        #pragma unroll
        for (int nt = 0; nt < 4; ++nt) {
            bf16x8 b = *(const bf16x8*)
                &sh.wt[(nt * 16 + ln) * FIN + (k0 ^ ((ln & 7) << 3))];
            acc[nt] = __builtin_amdgcn_mfma_f32_16x16x32_bf16(a, b, acc[nt], 0, 0, 0);
        }
    }

    // epilogue: D[m=q*4+reg][n=ln]; scale by t[row]; store bf16
    #pragma unroll
    for (int reg = 0; reg < 4; ++reg) {
        int r = rowb + q * 4 + reg;
        if (r < N) {
            float tv = t[r];
            #pragma unroll
            for (int nt = 0; nt < 4; ++nt)
                support[(size_t)r * FOUT + nt * 16 + ln] =
                    f32_to_bf16_rne(acc[nt][reg] * tv);
        }
    }
}

// ---------------------------------------------------------------------------
// scatter: per chunk, LDS-stage records + local hist, reserve per-bucket
// ranges via ONE returning atomicAdd per present bucket, place via LDS
// cursors. tmp stays globally bucket-contiguous.
// rec = {src | (d&63)<<16, ev_bits}   (src < 65536: N = 50000 ok)
// ---------------------------------------------------------------------------
__global__ __launch_bounds__(256) void scatter_kernel(
    const int* __restrict__ src, const int* __restrict__ dst,
    const float* __restrict__ ev, int* __restrict__ cur,
    int2* __restrict__ tmp, int E, int NBUK)
{
    __shared__ int2   stage[EPB];        // 16 KB
    __shared__ ushort bkt[EPB];          // 4 KB
    __shared__ int    h[NBUK_MAX];       // 3.2 KB
    __shared__ int    c[NBUK_MAX];       // 3.2 KB

    const int tid = threadIdx.x;
    const int e0  = blockIdx.x * EPB;

    for (int i = tid; i < NBUK; i += 256) h[i] = 0;
    __syncthreads();

    // pass 1: stage + local count
    for (int i = tid; i < EPB; i += 256) {
        int e = e0 + i;
        if (e < E) {
            int d = dst[e];
            int j = d >> 6;
            stage[i] = make_int2(src[e] | ((d & (NPB - 1)) << 16),
                                 __float_as_int(ev[e]));
            bkt[i] = (ushort)j;
            atomicAdd(&h[j], 1);
        } else {
            bkt[i] = 0xFFFF;
        }
    }
    __syncthreads();

    // pass 2: reserve contiguous ranges in each bucket's global region
    for (int j = tid; j < NBUK; j += 256) {
        int hj = h[j];
        if (hj) c[j] = atomicAdd(&cur[j], hj);
    }
    __syncthreads();

    // pass 3: place
    for (int i = tid; i < EPB; i += 256) {
        if (bkt[i] != 0xFFFF) {
            int pos = atomicAdd(&c[bkt[i]], 1);
            tmp[pos] = stage[i];
        }
    }
}

// ---------------------------------------------------------------------------
// bucket_gather: one block per 64-node bucket. tmp read once into LDS;
// count -> wave-0 shfl scan (64 wide) -> reorder -> register-walk with
// 8-deep MLP and wave-uniform node-boundary flush. No float atomics.
// ---------------------------------------------------------------------------
__global__ __launch_bounds__(256) void bucket_gather_kernel(
    const int* __restrict__ bases, const int2* __restrict__ tmp,
    const ushort* __restrict__ support, const float* __restrict__ bias,
    float* __restrict__ out, int E, int N, int NBUK)
{
    __shared__ int2 raw[CAP];           // 11 KB
    __shared__ int2 sorted[CAP];        // 11 KB
    __shared__ int  cnt[NPB];
    __shared__ int  starts[NPB + 1];
    __shared__ int  cur[NPB];

    const int tid   = threadIdx.x;
    const int w     = tid >> 6;
    const int lane  = tid & 63;
    const int B     = blockIdx.x;
    const int node0 = B * NPB;

    const int base   = bases[B];
    const int endB   = bases[B + 1];
    const int nrec   = endB - base;
    const int placed = (nrec < CAP) ? nrec : CAP;

    if (tid < NPB) cnt[tid] = 0;
    __syncthreads();

    // single global read of tmp: stage + count
    for (int i = tid; i < placed; i += 256) {
        int2 r = tmp[base + i];
        raw[i] = r;
        atomicAdd(&cnt[(r.x >> 16) & (NPB - 1)], 1);
    }
    __syncthreads();

    // wave-0 shfl scan over 64 counters
    if (tid < 64) {
        int v   = cnt[tid];
        int val = v;
        #pragma unroll
        for (int d = 1; d < NPB; d <<= 1) {
            int n = __shfl_up(val, d);
            if (tid >= d) val += n;
        }
        starts[tid] = val - v;
        cur[tid]    = val - v;
        if (tid == 0) starts[NPB] = placed;
    }
    __syncthreads();

    // reorder LDS -> LDS
    for (int i = tid; i < placed; i += 256) {
        int2 r  = raw[i];
        int pos = atomicAdd(&cur[(r.x >> 16) & (NPB - 1)], 1);
        sorted[pos] = r;
    }
    __syncthreads();

    // walk: wave w owns nodes [w*16, (w+1)*16) == records [rbeg, rend)
    const float bv = bias[lane];
    const int rbeg = starts[w * 16];
    const int rend = starts[w * 16 + 16];

    float accv = 0.f;
    int   curn = -1;

    int i = rbeg;
    // 8-deep MLP: issue 8 independent support-row gathers, then walk.
    while (i + 8 <= rend) {
        int2 r[8];
        #pragma unroll
        for (int u = 0; u < 8; ++u) r[u] = sorted[i + u];
        float v[8];
        #pragma unroll
        for (int u = 0; u < 8; ++u)
            v[u] = bf16_to_f32(support[(size_t)(r[u].x & 0xFFFF) * FOUT + lane]);
        #pragma unroll
        for (int u = 0; u < 8; ++u) {
            int n = (r[u].x >> 16) & (NPB - 1);     // wave-uniform
            if (n != curn) {
                if (curn >= 0 && node0 + curn < N)
                    out[(size_t)(node0 + curn) * FOUT + lane] = accv + bv;
                curn = n;
                accv = 0.f;
            }
            accv += v[u] * __int_as_float(r[u].y);
        }
        i += 8;
    }
    while (i < rend) {
        int2 a = sorted[i];
        float va = bf16_to_f32(support[(size_t)(a.x & 0xFFFF) * FOUT + lane]);
        int n = (a.x >> 16) & (NPB - 1);
        if (n != curn) {
            if (curn >= 0 && node0 + curn < N)
                out[(size_t)(node0 + curn) * FOUT + lane] = accv + bv;
            curn = n;
            accv = 0.f;
        }
        accv += va * __int_as_float(a.y);
        ++i;
    }
    if (curn >= 0 && node0 + curn < N)
        out[(size_t)(node0 + curn) * FOUT + lane] = accv + bv;

    // zero-count nodes get bias rows
    for (int n = w; n < NPB; n += 4) {
        int node = node0 + n;
        if (node < N && cnt[n] == 0)
            out[(size_t)node * FOUT + lane] = bv;
    }

    // overflow fallback (never triggers at this size; kept for correctness)
    if (nrec > CAP) {
        __threadfence();
        __syncthreads();
        for (int j = base + CAP + tid; j < endB; j += 256) {
            int2 r = tmp[j];
            int node = node0 + ((r.x >> 16) & (NPB - 1));
            float wgt = __int_as_float(r.y);
            for (int f = 0; f < FOUT; ++f) {
                float v = bf16_to_f32(support[(size_t)(r.x & 0xFFFF) * FOUT + f]);
                atomicAdd(&out[(size_t)node * FOUT + f], v * wgt);
            }
        }
    }
}

extern "C" void kernel_launch(void* const* d_in, const int* in_sizes, int n_in,
                              void* d_out, int out_size, void* d_ws, size_t ws_size,
                              hipStream_t stream) {
    const float* x    = (const float*)d_in[0];
    const float* t    = (const float*)d_in[1];
    const int*   src  = (const int*)d_in[2];
    const int*   dst  = (const int*)d_in[3];
    const float* ev   = (const float*)d_in[4];
    const float* W    = (const float*)d_in[5];
    const float* bias = (const float*)d_in[6];
    float* out = (float*)d_out;

    const int N = in_sizes[1];   // 50000
    const int E = in_sizes[2];   // 800000

    char*   ws      = (char*)d_ws;
    ushort* support = (ushort*)ws;
    int*    tot     = (int*)(ws + OFF_TOT);
    int*    done    = (int*)(ws + OFF_DONE);
    int*    bases   = (int*)(ws + OFF_BASES);
    int*    cur     = (int*)(ws + OFF_CUR);
    int2*   tmp     = (int2*)(ws + OFF_TMP);

    const int GB   = (N + TILE_ROWS - 1) / TILE_ROWS;       // 782
    const int SBP  = (E + EPB - 1) / EPB;                   // 391
    const int NBUK = (N + NPB - 1) / NPB;                   // 782

    // zero bucket totals + done counter (3.3 KB, graph-capturable)
    hipMemsetAsync(ws + OFF_TOT, 0, OFF_BASES - OFF_TOT, stream);

    // 1) fused: bucket totals (hist first) + MFMA gemm; last hist block
    //    scans -> bases/cur (overlapped with gemm blocks)
    gemm_hist_kernel<<<GB + SBP, 256, 0, stream>>>(
        x, t, W, support, N, dst, tot, done, bases, cur, E, SBP, NBUK, GB);

    // 2) scatter into bucket-ordered tmp (global cursor reservation)
    scatter_kernel<<<SBP, 256, 0, stream>>>(src, dst, ev, cur, tmp, E, NBUK);

    // 3) per-bucket LDS sort + register-walk accumulate -> out (+bias)
    bucket_gather_kernel<<<NBUK, 256, 0, stream>>>(
        bases, tmp, support, bias, out, E, N, NBUK);
}

// Round 4
// 141.658 us; speedup vs baseline: 1.3867x; 1.0682x over previous
//
#include <hip/hip_runtime.h>
#include <hip/hip_bf16.h>

#define FIN 128
#define FOUT 64
#define TILE_ROWS 64       // rows per gemm block = 4 waves x 16

#define EPB 2048           // edges per scatter chunk
#define NPB 64             // nodes per bucket (d >> 6)
#define NBUK_MAX 800
#define CAP 1408           // fixed records region per bucket (mean 1024, +12 sigma)

// Workspace layout (bytes), ws >= 268 MB:
//   [0, 6,400,000)         support : N*64 bf16
//   OFF_CUR   +3,200       cur     : NBUK int (bucket fill counters)
//   OFF_OVFC  +64          ovfc    : 1 int   (overflow count)
//   OFF_TMP   +9,011,200   tmp     : NBUK_MAX*CAP int2, fixed-stride regions
//   OFF_OVF   +12,800,000  ovf     : E int4 {recx, recy, bucket, pad}
#define OFF_CUR   6400000
#define OFF_OVFC  6403200
#define OFF_TMP   6403264
#define OFF_OVF   15414464

typedef short bf16x8 __attribute__((ext_vector_type(8)));
typedef float f32x4  __attribute__((ext_vector_type(4)));

__device__ inline ushort f32_to_bf16_rne(float f) {
    unsigned u = __float_as_uint(f);
    u += 0x7FFFu + ((u >> 16) & 1u);
    return (ushort)(u >> 16);
}
__device__ inline float bf16_to_f32(ushort h) {
    return __uint_as_float((unsigned)h << 16);
}

// ---------------------------------------------------------------------------
// Fused, independent branches (no intra-kernel ordering, no fences):
//   blocks [0,GB):       MFMA gemm (W staged to LDS bf16, transposed+swizzled)
//   blocks [GB,GB+SBP):  scatter chunk -> fixed-CAP bucket regions in tmp.
// Scatter: LDS hist of the chunk -> ONE returning global atomicAdd per
// present bucket (range reservation) -> place via LDS cursors.
// rec = {src | (d&63)<<16, ev_bits}   (src < 65536: N = 50000 ok)
// ---------------------------------------------------------------------------
union __align__(16) K1Sh {
    ushort wt[FOUT * FIN];                       // 16 KB (gemm: WT[n][k] swz)
    struct { int h[NBUK_MAX]; int c[NBUK_MAX]; } sc;  // 6.4 KB (scatter)
};

__global__ __launch_bounds__(256) void gemm_scatter_kernel(
    const float* __restrict__ x, const float* __restrict__ t,
    const float* __restrict__ W, ushort* __restrict__ support, int N,
    const int* __restrict__ src, const int* __restrict__ dst,
    const float* __restrict__ ev, int* __restrict__ cur,
    int2* __restrict__ tmp, int* __restrict__ ovfc, int4* __restrict__ ovf,
    int E, int SBP, int NBUK, int GB)
{
    __shared__ K1Sh sh;
    const int tid = threadIdx.x;

    if (blockIdx.x >= (unsigned)GB) {
        // ---- scatter branch ----
        const int chunk = blockIdx.x - GB;
        const int e0    = chunk * EPB;

        for (int i = tid; i < NBUK; i += 256) sh.sc.h[i] = 0;
        __syncthreads();

        // pass 1: local bucket counts
        for (int i = tid; i < EPB; i += 256) {
            int e = e0 + i;
            if (e < E) atomicAdd(&sh.sc.h[dst[e] >> 6], 1);
        }
        __syncthreads();

        // pass 2: reserve a contiguous slice of each present bucket's region
        for (int j = tid; j < NBUK; j += 256) {
            int hj = sh.sc.h[j];
            if (hj) sh.sc.c[j] = atomicAdd(&cur[j], hj);
        }
        __syncthreads();

        // pass 3: place (dst re-read is L2-hot)
        for (int i = tid; i < EPB; i += 256) {
            int e = e0 + i;
            if (e < E) {
                int d = dst[e];
                int j = d >> 6;
                int s = atomicAdd(&sh.sc.c[j], 1);
                int2 rec = make_int2(src[e] | ((d & (NPB - 1)) << 16),
                                     __float_as_int(ev[e]));
                if (s < CAP) {
                    tmp[(size_t)j * CAP + s] = rec;
                } else {                 // never at this size; kept correct
                    int o = atomicAdd(ovfc, 1);
                    if (o < E) ovf[o] = make_int4(rec.x, rec.y, j, 0);
                }
            }
        }
        return;
    }

    // ---- MFMA gemm branch ----
    const int gb   = blockIdx.x;
    const int lane = tid & 63;
    const int w    = tid >> 6;          // wave 0..3
    const int ln   = lane & 15;
    const int q    = lane >> 4;         // quad 0..3
    const int rowb = gb * TILE_ROWS + w * 16;
    const int arow = rowb + ln;

    // Stage W -> LDS bf16, transposed WT[n][k]; 16B slot XOR-swizzled by n&7.
    for (int idx = tid; idx < FIN * FOUT; idx += 256) {
        int k = idx >> 6;          // 0..127   (idx = k*FOUT + n)
        int n = idx & 63;          // 0..63
        sh.wt[n * FIN + (k ^ ((n & 7) << 3))] = f32_to_bf16_rne(W[idx]);
    }
    __syncthreads();

    f32x4 acc[4];
    #pragma unroll
    for (int nt = 0; nt < 4; ++nt)
        #pragma unroll
        for (int r = 0; r < 4; ++r) acc[nt][r] = 0.f;

    const bool aok = (arow < N);
    const float* xrow = &x[(size_t)arow * FIN];

    #pragma unroll
    for (int kc = 0; kc < 4; ++kc) {
        float xs[8];
        #pragma unroll
        for (int j = 0; j < 8; ++j) xs[j] = 0.f;
        if (aok) {
            float4 x0 = *(const float4*)&xrow[kc * 32 + q * 8];
            float4 x1 = *(const float4*)&xrow[kc * 32 + q * 8 + 4];
            xs[0] = x0.x; xs[1] = x0.y; xs[2] = x0.z; xs[3] = x0.w;
            xs[4] = x1.x; xs[5] = x1.y; xs[6] = x1.z; xs[7] = x1.w;
        }
        bf16x8 a;
        #pragma unroll
        for (int j = 0; j < 8; ++j) a[j] = (short)f32_to_bf16_rne(xs[j]);

        const int k0 = kc * 32 + q * 8;
        #pragma unroll
        for (int nt = 0; nt < 4; ++nt) {
            bf16x8 b = *(const bf16x8*)
                &sh.wt[(nt * 16 + ln) * FIN + (k0 ^ ((ln & 7) << 3))];
            acc[nt] = __builtin_amdgcn_mfma_f32_16x16x32_bf16(a, b, acc[nt], 0, 0, 0);
        }
    }

    // epilogue: D[m=q*4+reg][n=ln]; scale by t[row]; store bf16
    #pragma unroll
    for (int reg = 0; reg < 4; ++reg) {
        int r = rowb + q * 4 + reg;
        if (r < N) {
            float tv = t[r];
            #pragma unroll
            for (int nt = 0; nt < 4; ++nt)
                support[(size_t)r * FOUT + nt * 16 + ln] =
                    f32_to_bf16_rne(acc[nt][reg] * tv);
        }
    }
}

// ---------------------------------------------------------------------------
// bucket_gather: one block per 64-node bucket. Region [B*CAP, B*CAP+placed)
// read once into LDS; count -> wave-0 shfl scan -> reorder -> register-walk
// with 8-deep MLP and wave-uniform node-boundary flush. No float atomics in
// the normal path. Overflow tail (never taken) applied by the owning block.
// ---------------------------------------------------------------------------
__global__ __launch_bounds__(256) void bucket_gather_kernel(
    const int* __restrict__ curg, const int2* __restrict__ tmp,
    const ushort* __restrict__ support, const float* __restrict__ bias,
    float* __restrict__ out, const int* __restrict__ ovfc,
    const int4* __restrict__ ovf, int E, int N, int NBUK)
{
    __shared__ int2 raw[CAP];           // 11 KB
    __shared__ int2 sorted[CAP];        // 11 KB
    __shared__ int  cnt[NPB];
    __shared__ int  starts[NPB + 1];
    __shared__ int  cur[NPB];
    __shared__ int  novs;

    const int tid   = threadIdx.x;
    const int w     = tid >> 6;
    const int lane  = tid & 63;
    const int B     = blockIdx.x;
    const int node0 = B * NPB;

    const int base   = B * CAP;
    const int tot    = curg[B];
    const int placed = (tot < CAP) ? tot : CAP;

    if (tid < NPB) cnt[tid] = 0;
    __syncthreads();

    // single global read of tmp region: stage + count
    for (int i = tid; i < placed; i += 256) {
        int2 r = tmp[base + i];
        raw[i] = r;
        atomicAdd(&cnt[(r.x >> 16) & (NPB - 1)], 1);
    }
    __syncthreads();

    // wave-0 shfl scan over 64 counters
    if (tid < 64) {
        int v   = cnt[tid];
        int val = v;
        #pragma unroll
        for (int d = 1; d < NPB; d <<= 1) {
            int n = __shfl_up(val, d);
            if (tid >= d) val += n;
        }
        starts[tid] = val - v;
        cur[tid]    = val - v;
        if (tid == 0) starts[NPB] = placed;
    }
    __syncthreads();

    // reorder LDS -> LDS
    for (int i = tid; i < placed; i += 256) {
        int2 r  = raw[i];
        int pos = atomicAdd(&cur[(r.x >> 16) & (NPB - 1)], 1);
        sorted[pos] = r;
    }
    __syncthreads();

    // walk: wave w owns nodes [w*16, (w+1)*16) == records [rbeg, rend)
    const float bv = bias[lane];
    const int rbeg = starts[w * 16];
    const int rend = starts[w * 16 + 16];

    float accv = 0.f;
    int   curn = -1;

    int i = rbeg;
    // 8-deep MLP: issue 8 independent support-row gathers, then walk.
    while (i + 8 <= rend) {
        int2 r[8];
        #pragma unroll
        for (int u = 0; u < 8; ++u) r[u] = sorted[i + u];
        float v[8];
        #pragma unroll
        for (int u = 0; u < 8; ++u)
            v[u] = bf16_to_f32(support[(size_t)(r[u].x & 0xFFFF) * FOUT + lane]);
        #pragma unroll
        for (int u = 0; u < 8; ++u) {
            int n = (r[u].x >> 16) & (NPB - 1);     // wave-uniform
            if (n != curn) {
                if (curn >= 0 && node0 + curn < N)
                    out[(size_t)(node0 + curn) * FOUT + lane] = accv + bv;
                curn = n;
                accv = 0.f;
            }
            accv += v[u] * __int_as_float(r[u].y);
        }
        i += 8;
    }
    while (i < rend) {
        int2 a = sorted[i];
        float va = bf16_to_f32(support[(size_t)(a.x & 0xFFFF) * FOUT + lane]);
        int n = (a.x >> 16) & (NPB - 1);
        if (n != curn) {
            if (curn >= 0 && node0 + curn < N)
                out[(size_t)(node0 + curn) * FOUT + lane] = accv + bv;
            curn = n;
            accv = 0.f;
        }
        accv += va * __int_as_float(a.y);
        ++i;
    }
    if (curn >= 0 && node0 + curn < N)
        out[(size_t)(node0 + curn) * FOUT + lane] = accv + bv;

    // zero-count nodes get bias rows
    for (int n = w; n < NPB; n += 4) {
        int node = node0 + n;
        if (node < N && cnt[n] == 0)
            out[(size_t)node * FOUT + lane] = bv;
    }

    // overflow tail: never taken at this size; kept for correctness.
    // Owning block applies its bucket's overflow via atomicAdd AFTER its own
    // plain stores; guarded __threadfence makes those stores visible to the
    // RMWs (fence executes only when overflow actually occurred).
    __syncthreads();
    if (tid == 0) novs = *ovfc;
    __syncthreads();
    int nov = novs;
    if (nov > 0) {
        if (nov > E) nov = E;
        __threadfence();
        for (int k = w; k < nov; k += 4) {
            int4 r = ovf[k];
            if (r.z == B) {
                int node = node0 + ((r.x >> 16) & (NPB - 1));
                if (node < N) {
                    float v = bf16_to_f32(
                        support[(size_t)(r.x & 0xFFFF) * FOUT + lane]);
                    atomicAdd(&out[(size_t)node * FOUT + lane],
                              v * __int_as_float(r.y));
                }
            }
        }
    }
}

extern "C" void kernel_launch(void* const* d_in, const int* in_sizes, int n_in,
                              void* d_out, int out_size, void* d_ws, size_t ws_size,
                              hipStream_t stream) {
    const float* x    = (const float*)d_in[0];
    const float* t    = (const float*)d_in[1];
    const int*   src  = (const int*)d_in[2];
    const int*   dst  = (const int*)d_in[3];
    const float* ev   = (const float*)d_in[4];
    const float* W    = (const float*)d_in[5];
    const float* bias = (const float*)d_in[6];
    float* out = (float*)d_out;

    const int N = in_sizes[1];   // 50000
    const int E = in_sizes[2];   // 800000

    char*   ws      = (char*)d_ws;
    ushort* support = (ushort*)ws;
    int*    cur     = (int*)(ws + OFF_CUR);
    int*    ovfc    = (int*)(ws + OFF_OVFC);
    int2*   tmp     = (int2*)(ws + OFF_TMP);
    int4*   ovf     = (int4*)(ws + OFF_OVF);

    const int GB   = (N + TILE_ROWS - 1) / TILE_ROWS;       // 782
    const int SBP  = (E + EPB - 1) / EPB;                   // 391
    const int NBUK = (N + NPB - 1) / NPB;                   // 782

    // zero bucket cursors + overflow count (3.3 KB, graph-capturable)
    hipMemsetAsync(ws + OFF_CUR, 0, OFF_TMP - OFF_CUR, stream);

    // 1) fused independent branches: MFMA gemm || fixed-CAP scatter
    gemm_scatter_kernel<<<GB + SBP, 256, 0, stream>>>(
        x, t, W, support, N, src, dst, ev, cur, tmp, ovfc, ovf,
        E, SBP, NBUK, GB);

    // 2) per-bucket LDS sort + register-walk accumulate -> out (+bias)
    bucket_gather_kernel<<<NBUK, 256, 0, stream>>>(
        cur, tmp, support, bias, out, ovfc, ovf, E, N, NBUK);
}